// Round 7
// baseline (115.513 us; speedup 1.0000x reference)
//
#include <hip/hip_runtime.h>
#include <math.h>

#define BOS_TAG 62
#define EOS_TAG 63
#define S_LEN   1024
#define NCH     64
#define CH      16          // S_LEN / NCH
#define WPB     4           // NCH/16: fwd waves per batch (same for bwd)
#define LN2F    0.69314718055994530942f

typedef short  short8 __attribute__((ext_vector_type(8)));
typedef unsigned short ushort4v __attribute__((ext_vector_type(4)));
typedef float  f32x4  __attribute__((ext_vector_type(4)));

template <int CTRL>
__device__ __forceinline__ int dpp_mov(int v) {
  return __builtin_amdgcn_update_dpp(v, v, CTRL, 0xf, 0xf, false);
}
template <int CTRL>
__device__ __forceinline__ float dpp_fmax_step(float v) {
  return fmaxf(v, __int_as_float(dpp_mov<CTRL>(__float_as_int(v))));
}
__device__ __forceinline__ float wave_fmax_all(float v) {
  v = dpp_fmax_step<0x111>(v); v = dpp_fmax_step<0x112>(v);
  v = dpp_fmax_step<0x114>(v); v = dpp_fmax_step<0x118>(v);
  v = dpp_fmax_step<0x142>(v); v = dpp_fmax_step<0x143>(v);
  return __int_as_float(__builtin_amdgcn_readlane(__float_as_int(v), 63));
}
__device__ __forceinline__ float wave_sum(float v) {
#pragma unroll
  for (int off = 32; off; off >>= 1) v += __shfl_xor(v, off, 64);
  return v;
}
__device__ __forceinline__ unsigned short f2bf(float v) {   // round-half-up (positive vals)
  return (unsigned short)((__float_as_uint(v) + 0x8000u) >> 16);
}
__device__ __forceinline__ float bf2f(unsigned short u) {
  return __uint_as_float(((unsigned)u) << 16);
}
__device__ __forceinline__ int seq_len64(const float* mb, int l) {
  float lenf = 0.f;
  for (int t = l; t < S_LEN; t += 64) lenf += mb[t];
  lenf = wave_sum(lenf);
  int len = (int)(lenf + 0.5f);
  return max(1, min(S_LEN, len));
}

// ===== MFMA chunk kernel: 16 chains (rows) per wave, V in per-wave LDS =====
// wave w: dir = w&1 (0 fwd / 1 bwd), idx = w>>1, b = idx/WPB, half = idx%WPB.
// Row r <-> chunk kg = half*16 + r.
// State tiling: MFMA output tile n, lane-col c <-> state 4c+n  (so each lane's
// 4 D-states are contiguous -> float4 emission loads + b64 LDS writes).
// A-side k-slot (kc,g,j) <-> state 32kc+8g+j (R6-verified). LDS layout:
// bf16 word (row*64 + state), byte-swizzled ^((row&7)<<4).
__global__ __launch_bounds__(256) void crf_chunk_mfma(
    const float* __restrict__ em, const int* __restrict__ tags,
    const float* __restrict__ mask, const float* __restrict__ trans,
    unsigned short* __restrict__ Vf, unsigned short* __restrict__ Vb,
    float* __restrict__ sf, float* __restrict__ sb,
    float* __restrict__ sca, float* __restrict__ m0a, int B)
{
  __shared__ unsigned short smem[4][16 * 64];
  const int wv = threadIdx.x >> 6;
  const int l  = threadIdx.x & 63;
  const int w  = blockIdx.x * 4 + wv;
  const int nwaves = 2 * B * WPB;
  if (w >= nwaves) return;
  const int dir  = w & 1;
  const int idx  = w >> 1;
  const int b    = idx / WPB;
  const int half = idx % WPB;
  unsigned short* smw = smem[wv];
  const float* embase = em + (size_t)b * S_LEN * 64;
  const int g = l >> 4, c = l & 15;

  const int len = seq_len64(mask + (size_t)b * S_LEN, l);

  // ---- B fragments (bf16 exp(trans)), state-tiled: col (n,c) = state 4c+n.
  // fwd:  B[k][col] = P[k][col]      = exp(trans[k*64 + col])
  // bwd:  B[k][col] = P^T[k][col]    = exp(trans[col*64 + k])
  short8 Bf[2][4];
#pragma unroll
  for (int kc = 0; kc < 2; ++kc)
#pragma unroll
    for (int n = 0; n < 4; ++n) {
      short8 f;
#pragma unroll
      for (int j = 0; j < 8; ++j) {
        int k = kc * 32 + g * 8 + j, col = 4 * c + n;
        float tv = dir ? trans[col * 64 + k] : trans[k * 64 + col];
        f[j] = (short)f2bf(__expf(tv));
      }
      Bf[kc][n] = f;
    }

  // ---- init V rows (swizzled LDS [16][64] bf16) ----
#pragma unroll
  for (int r = 0; r < 16; ++r) {
    float v = 1.0f;
    if (dir == 0 && half == 0 && r == 0) {
      float a0 = trans[BOS_TAG * 64 + l] + embase[l];
      float m0 = wave_fmax_all(a0);
      v = __expf(a0 - m0);
      if (l == 0) m0a[b] = m0;
    }
    smw[(r * 64 + l) ^ ((r & 7) << 3)] = f2bf(v);
  }

  // ---- per-row step counts; pre-save empty rows; find the partial row ----
  unsigned short* Vout = dir ? Vb : Vf;
  float* sout = dir ? sb : sf;
  int fstep[16];
  int ps = -1, pr = -1;
#pragma unroll
  for (int r = 0; r < 16; ++r) {
    int kg = half * 16 + r;
    int tend = min((kg + 1) * CH, len - 1);
    fstep[r] = tend - (kg * CH + 1);
    if (fstep[r] < 0) {
      Vout[((size_t)b * NCH + kg) * 64 + l] = 0x3F80; // bf16 1.0
      if (l == 0) sout[b * NCH + kg] = 0.f;
    }
    if (fstep[r] >= 0 && fstep[r] < CH - 1) { ps = fstep[r]; pr = r; }
  }

  const int byteA0 = (c * 128 + g * 16) ^ ((c & 7) << 4);
  const int byteA1 = (c * 128 + 64 + g * 16) ^ ((c & 7) << 4);
  int sigma = 0;

  auto renorm16 = [&](float* d) {
    float m = d[0];
#pragma unroll
    for (int i = 1; i < 16; ++i) m = fmaxf(m, d[i]);
    m = wave_fmax_all(m);
    int e = ((__float_as_int(m) >> 23) & 0xff) - 127;
    float s = __int_as_float((127 - e) << 23);
#pragma unroll
    for (int i = 0; i < 16; ++i) d[i] *= s;
    sigma += e;
  };
  auto save_row = [&](int r) {
    unsigned short v = smw[(r * 64 + l) ^ ((r & 7) << 3)];
    int kg = half * 16 + r;
    Vout[((size_t)b * NCH + kg) * 64 + l] = v;
    if (l == 0) sout[b * NCH + kg] = (float)sigma;
  };
  auto write_d = [&](const float* d) {
#pragma unroll
    for (int reg = 0; reg < 4; ++reg) {
      int row = g * 4 + reg;
      ushort4v wq;
#pragma unroll
      for (int n = 0; n < 4; ++n) wq[n] = f2bf(d[reg * 4 + n]);
      *reinterpret_cast<ushort4v*>(
          (char*)smw + ((row * 128 + c * 8) ^ ((row & 7) << 4))) = wq;
    }
  };

  if (dir == 0) {
    // ---- gold-path score partial over this wave's t-range ----
    {
      const int* tb = tags + (size_t)b * S_LEN;
      int lo = half * (16 * CH) + 1;
      int hi = min(half * (16 * CH) + 16 * CH, len - 1);
      float sc = 0.f;
      for (int t = lo + l; t <= hi; t += 64)
        sc += embase[(size_t)t * 64 + tb[t]] + trans[tb[t - 1] * 64 + tb[t]];
      sc = wave_sum(sc);
      if (half == 0) sc += trans[BOS_TAG * 64 + tb[0]] + embase[tb[0]];
      if (l == 0) sca[b * WPB + half] = sc;
    }

    int tb0[4];
#pragma unroll
    for (int reg = 0; reg < 4; ++reg) tb0[reg] = (half * 16 + g * 4 + reg) * CH + 1;

    auto loadF = [&](float4* e, int tl) {
#pragma unroll
      for (int reg = 0; reg < 4; ++reg) {
        int tr = min(tb0[reg] + tl, S_LEN - 1);
        e[reg] = *reinterpret_cast<const float4*>(embase + (size_t)tr * 64 + 4 * c);
      }
    };
    auto bodyF = [&](const float4* e, int tl) {
      short8 a0 = *reinterpret_cast<const short8*>((const char*)smw + byteA0);
      short8 a1 = *reinterpret_cast<const short8*>((const char*)smw + byteA1);
      f32x4 acc[4];
#pragma unroll
      for (int n = 0; n < 4; ++n) {
        f32x4 z = {0.f, 0.f, 0.f, 0.f};
        z = __builtin_amdgcn_mfma_f32_16x16x32_bf16(a0, Bf[0][n], z, 0, 0, 0);
        acc[n] = __builtin_amdgcn_mfma_f32_16x16x32_bf16(a1, Bf[1][n], z, 0, 0, 0);
      }
      float d[16];
#pragma unroll
      for (int reg = 0; reg < 4; ++reg) {
        d[reg * 4 + 0] = acc[0][reg] * __expf(e[reg].x);
        d[reg * 4 + 1] = acc[1][reg] * __expf(e[reg].y);
        d[reg * 4 + 2] = acc[2][reg] * __expf(e[reg].z);
        d[reg * 4 + 3] = acc[3][reg] * __expf(e[reg].w);
      }
      if ((tl & 3) == 3 || tl == CH - 1) renorm16(d);
      write_d(d);
      if (tl == ps) save_row(pr);
    };

    float4 eA[4], eB2[4];
    loadF(eA, 0);
#pragma unroll
    for (int tl = 0; tl < CH; tl += 2) {
      loadF(eB2, tl + 1);
      bodyF(eA, tl);
      if (tl + 2 < CH) loadF(eA, tl + 2);
      bodyF(eB2, tl + 1);
    }
#pragma unroll
    for (int r = 0; r < 16; ++r)
      if (fstep[r] == CH - 1) save_row(r);
  } else {
    // ---- bwd: A rows are chains rc = c; E applied on A side (contiguous states)
    const int tendl = min((half * 16 + c + 1) * CH, len - 1);

    auto loadB = [&](float4* e, int tl) {
      int tr = max(tendl - tl, 0);
      const float* rowp = embase + (size_t)tr * 64;
      e[0] = *reinterpret_cast<const float4*>(rowp + 8 * g);
      e[1] = *reinterpret_cast<const float4*>(rowp + 8 * g + 4);
      e[2] = *reinterpret_cast<const float4*>(rowp + 32 + 8 * g);
      e[3] = *reinterpret_cast<const float4*>(rowp + 32 + 8 * g + 4);
    };
    auto bodyB = [&](const float4* e, int tl) {
      short8 ar0 = *reinterpret_cast<const short8*>((const char*)smw + byteA0);
      short8 ar1 = *reinterpret_cast<const short8*>((const char*)smw + byteA1);
      short8 a0, a1;
#pragma unroll
      for (int j = 0; j < 4; ++j) {
        a0[j]     = (short)f2bf(bf2f((unsigned short)ar0[j])     * __expf(((const float*)&e[0])[j]));
        a0[4 + j] = (short)f2bf(bf2f((unsigned short)ar0[4 + j]) * __expf(((const float*)&e[1])[j]));
        a1[j]     = (short)f2bf(bf2f((unsigned short)ar1[j])     * __expf(((const float*)&e[2])[j]));
        a1[4 + j] = (short)f2bf(bf2f((unsigned short)ar1[4 + j]) * __expf(((const float*)&e[3])[j]));
      }
      f32x4 acc[4];
#pragma unroll
      for (int n = 0; n < 4; ++n) {
        f32x4 z = {0.f, 0.f, 0.f, 0.f};
        z = __builtin_amdgcn_mfma_f32_16x16x32_bf16(a0, Bf[0][n], z, 0, 0, 0);
        acc[n] = __builtin_amdgcn_mfma_f32_16x16x32_bf16(a1, Bf[1][n], z, 0, 0, 0);
      }
      float d[16];
#pragma unroll
      for (int reg = 0; reg < 4; ++reg)
#pragma unroll
        for (int n = 0; n < 4; ++n) d[reg * 4 + n] = acc[n][reg];
      if ((tl & 3) == 3 || tl == CH - 1) renorm16(d);
      write_d(d);
      if (tl == ps) save_row(pr);
    };

    float4 eA[4], eB2[4];
    loadB(eA, 0);
#pragma unroll
    for (int tl = 0; tl < CH; tl += 2) {
      loadB(eB2, tl + 1);
      bodyB(eA, tl);
      if (tl + 2 < CH) loadB(eA, tl + 2);
      bodyB(eB2, tl + 1);
    }
#pragma unroll
    for (int r = 0; r < 16; ++r)
      if (fstep[r] == CH - 1) save_row(r);
  }
}

// ===== combine: rank-1 chunk stitching + score assembly =====
__global__ __launch_bounds__(256) void crf_combine(
    const float* __restrict__ mask, const int* __restrict__ tags,
    const float* __restrict__ trans,
    const unsigned short* __restrict__ Vf, const unsigned short* __restrict__ Vb,
    const float* __restrict__ sf, const float* __restrict__ sb,
    const float* __restrict__ sca, const float* __restrict__ m0a,
    float* __restrict__ nll, int B)
{
  const int b = blockIdx.x * 4 + (threadIdx.x >> 6);
  if (b >= B) return;
  const int l = threadIdx.x & 63;
  const int len = seq_len64(mask + (size_t)b * S_LEN, l);
  const int kb = (len >= 2) ? (len - 2) / CH : 0;

  const unsigned short* vf = Vf + (size_t)b * NCH * 64;
  const unsigned short* vb = Vb + (size_t)b * NCH * 64;
  const float tvec = __expf(trans[l * 64 + EOS_TAG]);

  float vf0 = bf2f(vf[l]);
  float lp;
  if (kb == 0) {
    lp = m0a[b] + LN2F * sf[b * NCH] + logf(wave_sum(vf0 * tvec));
  } else {
    lp = m0a[b] + LN2F * (sf[b * NCH] + sb[b * NCH + 1])
       + logf(wave_sum(vf0 * bf2f(vb[1 * 64 + l])));
    for (int k = 1; k < kb; ++k) {
      float vfk = bf2f(vf[(size_t)k * 64 + l]);
      lp += LN2F * sb[b * NCH + k + 1]
          + logf(wave_sum(vfk * bf2f(vb[(size_t)(k + 1) * 64 + l])))
          - logf(wave_sum(vfk));
    }
    float vfb = bf2f(vf[(size_t)kb * 64 + l]);
    lp += logf(wave_sum(vfb * tvec)) - logf(wave_sum(vfb));
  }

  float sc = 0.f;
#pragma unroll
  for (int h = 0; h < WPB; ++h) sc += sca[b * WPB + h];
  const int* tb = tags + (size_t)b * S_LEN;
  sc += trans[tb[len - 1] * 64 + EOS_TAG];

  if (l == 0) nll[b] = lp - sc;
}

__global__ __launch_bounds__(64) void crf_reduce(
    const float* __restrict__ nll, float* __restrict__ out, int B) {
  float s = 0.f;
  for (int i = threadIdx.x; i < B; i += 64) s += nll[i];
  s = wave_sum(s);
  if (threadIdx.x == 0) out[0] = s;
}

// ===== fallback: monolithic per-batch forward (VALU, linear space) =====
__global__ __launch_bounds__(64) void crf_mono(
    const float* __restrict__ em, const int* __restrict__ tags,
    const float* __restrict__ mask, const float* __restrict__ trans,
    float* __restrict__ partial)
{
  const int b = blockIdx.x;
  const int l = threadIdx.x;
  const float* emb = em + (size_t)b * S_LEN * 64;
  const int len = seq_len64(mask + (size_t)b * S_LEN, l);

  float p[64];
#pragma unroll
  for (int i = 0; i < 64; ++i) p[i] = __expf(trans[i * 64 + l]) * 0.015625f;

  const int* tb = tags + (size_t)b * S_LEN;
  float sc = 0.f;
  for (int tt = 1 + l; tt <= len - 1; tt += 64)
    sc += emb[(size_t)tt * 64 + tb[tt]] + trans[tb[tt - 1] * 64 + tb[tt]];
  sc = wave_sum(sc);
  sc += trans[BOS_TAG * 64 + tb[0]] + emb[tb[0]] + trans[tb[len - 1] * 64 + EOS_TAG];

  float a0 = trans[BOS_TAG * 64 + l] + emb[l];
  float m0 = wave_fmax_all(a0);
  float v = __expf(a0 - m0);
  int sigma = 0;
  for (int t = 1; t <= len - 1; ++t) {
    float E = __expf(emb[(size_t)t * 64 + l]);
    int xi = __float_as_int(v);
    float s0 = 0.f, s1 = 0.f, s2 = 0.f, s3 = 0.f;
#pragma unroll
    for (int i = 0; i < 64; i += 4) {
      s0 = fmaf(__int_as_float(__builtin_amdgcn_readlane(xi, i + 0)), p[i + 0], s0);
      s1 = fmaf(__int_as_float(__builtin_amdgcn_readlane(xi, i + 1)), p[i + 1], s1);
      s2 = fmaf(__int_as_float(__builtin_amdgcn_readlane(xi, i + 2)), p[i + 2], s2);
      s3 = fmaf(__int_as_float(__builtin_amdgcn_readlane(xi, i + 3)), p[i + 3], s3);
    }
    v = ((s0 + s1) + (s2 + s3)) * E;
    float m = wave_fmax_all(v);
    int e = ((__float_as_int(m) >> 23) & 0xff) - 127;
    sigma += e + 6;
    v *= __int_as_float((127 - e) << 23);
  }
  float tvec = __expf(trans[l * 64 + EOS_TAG]);
  float lp = m0 + LN2F * (float)sigma + logf(wave_sum(v * tvec));
  if (l == 0) partial[b] = lp - sc;
}

extern "C" void kernel_launch(void* const* d_in, const int* in_sizes, int n_in,
                              void* d_out, int out_size, void* d_ws, size_t ws_size,
                              hipStream_t stream) {
  const float* em = (const float*)d_in[0];
  const int* tags = (const int*)d_in[1];
  const float* mask = (const float*)d_in[2];
  const float* trans = (const float*)d_in[3];
  float* out = (float*)d_out;

  const int B = in_sizes[1] / S_LEN;

  // layout: floats [sf | sb | sca | m0a | nll], then ushort [Vf | Vb]
  const size_t nSig = (size_t)B * NCH;
  const size_t nFlt = 2 * nSig + (size_t)B * WPB + 2 * (size_t)B;
  const size_t nV   = (size_t)B * NCH * 64;
  const size_t need = nFlt * sizeof(float) + 2 * nV * sizeof(unsigned short);

  if (ws_size >= need) {
    float* sf  = (float*)d_ws;
    float* sb  = sf + nSig;
    float* sca = sb + nSig;
    float* m0a = sca + (size_t)B * WPB;
    float* nll = m0a + B;
    unsigned short* Vf = (unsigned short*)(nll + B);
    unsigned short* Vb = Vf + nV;

    const int nwaves = 2 * B * WPB;
    crf_chunk_mfma<<<(nwaves + 3) / 4, 256, 0, stream>>>(
        em, tags, mask, trans, Vf, Vb, sf, sb, sca, m0a, B);
    crf_combine<<<(B + 3) / 4, 256, 0, stream>>>(
        mask, tags, trans, Vf, Vb, sf, sb, sca, m0a, nll, B);
    crf_reduce<<<1, 64, 0, stream>>>(nll, out, B);
  } else {
    float* partial = (float*)d_ws;
    crf_mono<<<B, 64, 0, stream>>>(em, tags, mask, trans, partial);
    crf_reduce<<<1, 64, 0, stream>>>(partial, out, B);
  }
}

// Round 8
// 98.996 us; speedup vs baseline: 1.1668x; 1.1668x over previous
//
#include <hip/hip_runtime.h>
#include <math.h>

#define BOS_TAG 62
#define EOS_TAG 63
#define S_LEN   1024
#define NCH     64
#define CH      16          // S_LEN / NCH
#define WPB     4           // NCH/16: fwd waves per batch (same for bwd)
#define LN2F    0.69314718055994530942f

typedef short  short8 __attribute__((ext_vector_type(8)));
typedef unsigned short ushort4v __attribute__((ext_vector_type(4)));
typedef float  f32x4  __attribute__((ext_vector_type(4)));

template <int CTRL>
__device__ __forceinline__ int dpp_mov(int v) {
  return __builtin_amdgcn_update_dpp(v, v, CTRL, 0xf, 0xf, false);
}
template <int CTRL>
__device__ __forceinline__ float dpp_fmax_step(float v) {
  return fmaxf(v, __int_as_float(dpp_mov<CTRL>(__float_as_int(v))));
}
__device__ __forceinline__ float wave_fmax_all(float v) {
  v = dpp_fmax_step<0x111>(v); v = dpp_fmax_step<0x112>(v);
  v = dpp_fmax_step<0x114>(v); v = dpp_fmax_step<0x118>(v);
  v = dpp_fmax_step<0x142>(v); v = dpp_fmax_step<0x143>(v);
  return __int_as_float(__builtin_amdgcn_readlane(__float_as_int(v), 63));
}
template <int CTRL>
__device__ __forceinline__ float dpp_fadd_step(float v) {
  int t = __builtin_amdgcn_update_dpp(0, __float_as_int(v), CTRL, 0xf, 0xf, true);
  return v + __int_as_float(t);
}
// Exact wave-wide sum via DPP tree (VALU pipe; ~6 ops vs 6 ds_swizzle).
__device__ __forceinline__ float wave_sum_all(float v) {
  v = dpp_fadd_step<0x111>(v); v = dpp_fadd_step<0x112>(v);
  v = dpp_fadd_step<0x114>(v); v = dpp_fadd_step<0x118>(v);
  v = dpp_fadd_step<0x142>(v); v = dpp_fadd_step<0x143>(v);
  return __int_as_float(__builtin_amdgcn_readlane(__float_as_int(v), 63));
}
__device__ __forceinline__ unsigned short f2bf(float v) {   // round-half-up (positive vals)
  return (unsigned short)((__float_as_uint(v) + 0x8000u) >> 16);
}
__device__ __forceinline__ float bf2f(unsigned short u) {
  return __uint_as_float(((unsigned)u) << 16);
}
__device__ __forceinline__ float bflo(unsigned u) { return __uint_as_float(u << 16); }
__device__ __forceinline__ float bfhi(unsigned u) { return __uint_as_float(u & 0xffff0000u); }

// ===== prep: per-batch len, full gold-path score, alpha0 max =====
__global__ __launch_bounds__(256) void crf_prep(
    const float* __restrict__ em, const int* __restrict__ tags,
    const float* __restrict__ mask, const float* __restrict__ trans,
    int* __restrict__ lens, float* __restrict__ score, float* __restrict__ m0a)
{
  const int b = blockIdx.x;
  const int tid = threadIdx.x;
  const float* emb = em + (size_t)b * S_LEN * 64;
  const float* mb = mask + (size_t)b * S_LEN;
  const int* tb = tags + (size_t)b * S_LEN;

  float ms = 0.f, sc = 0.f;
  for (int t = tid; t < S_LEN; t += 256) {
    float m = mb[t];
    ms += m;
    if (t >= 1)
      sc += m * (emb[(size_t)t * 64 + tb[t]] + trans[tb[t - 1] * 64 + tb[t]]);
  }
  ms = wave_sum_all(ms);
  sc = wave_sum_all(sc);

  __shared__ float red[2][4];
  const int wid = tid >> 6;
  if ((tid & 63) == 0) { red[0][wid] = ms; red[1][wid] = sc; }
  __syncthreads();
  if (tid == 0) {
    float mt = red[0][0] + red[0][1] + red[0][2] + red[0][3];
    float st = red[1][0] + red[1][1] + red[1][2] + red[1][3];
    int len = (int)(mt + 0.5f);
    len = max(1, min(S_LEN, len));
    st += trans[BOS_TAG * 64 + tb[0]] + emb[tb[0]] + trans[tb[len - 1] * 64 + EOS_TAG];
    lens[b] = len;
    score[b] = st;
  }
  if (tid < 64) {
    float a0 = trans[BOS_TAG * 64 + tid] + emb[tid];
    float m0 = wave_fmax_all(a0);
    if (tid == 0) m0a[b] = m0;
  }
}

// ===== MFMA chunk kernel: 16 chains (rows) per wave, V in per-wave LDS =====
// wave w: dir = w&1 (0 fwd / 1 bwd), idx = w>>1, b = idx/WPB, half = idx%WPB.
// Row r <-> chunk kg = half*16 + r.
// State tiling: MFMA output tile n, lane-col c <-> state 4c+n.
// A-side k-slot (kc,g,j) <-> state 32kc+8g+j. LDS: bf16 word (row*64+state),
// byte-swizzled ^((row&7)<<4).  Emissions: depth-4 register pipeline,
// exp() applied at load, stored packed bf16 (8 VGPR per step-buffer).
__global__ __launch_bounds__(256) void crf_chunk_mfma(
    const float* __restrict__ em, const float* __restrict__ trans,
    const int* __restrict__ lens,
    unsigned short* __restrict__ Vf, unsigned short* __restrict__ Vb,
    float* __restrict__ sf, float* __restrict__ sb,
    const float* __restrict__ m0a, int B)
{
  __shared__ unsigned short smem[4][16 * 64];
  const int wv = threadIdx.x >> 6;
  const int l  = threadIdx.x & 63;
  const int w  = blockIdx.x * 4 + wv;
  const int nwaves = 2 * B * WPB;
  if (w >= nwaves) return;
  const int dir  = w & 1;
  const int idx  = w >> 1;
  const int b    = idx / WPB;
  const int half = idx % WPB;
  unsigned short* smw = smem[wv];
  const float* embase = em + (size_t)b * S_LEN * 64;
  const int g = l >> 4, c = l & 15;

  const int len = lens[b];

  // ---- B fragments (bf16 exp(trans)), state-tiled col = 4c+n ----
  short8 Bf[2][4];
#pragma unroll
  for (int kc = 0; kc < 2; ++kc)
#pragma unroll
    for (int n = 0; n < 4; ++n) {
      short8 f;
#pragma unroll
      for (int j = 0; j < 8; ++j) {
        int k = kc * 32 + g * 8 + j, col = 4 * c + n;
        float tv = dir ? trans[col * 64 + k] : trans[k * 64 + col];
        f[j] = (short)f2bf(__expf(tv));
      }
      Bf[kc][n] = f;
    }

  // ---- init V rows (swizzled LDS [16][64] bf16) ----
#pragma unroll
  for (int r = 0; r < 16; ++r) {
    float v = 1.0f;
    if (dir == 0 && half == 0 && r == 0) {
      float a0 = trans[BOS_TAG * 64 + l] + embase[l];
      v = __expf(a0 - m0a[b]);
    }
    smw[(r * 64 + l) ^ ((r & 7) << 3)] = f2bf(v);
  }

  // ---- per-row step counts; pre-save empty rows; find the partial row ----
  unsigned short* Vout = dir ? Vb : Vf;
  float* sout = dir ? sb : sf;
  int fstep[16];
  int ps = -1, pr = -1;
#pragma unroll
  for (int r = 0; r < 16; ++r) {
    int kg = half * 16 + r;
    int tend = min((kg + 1) * CH, len - 1);
    fstep[r] = tend - (kg * CH + 1);
    if (fstep[r] < 0) {
      Vout[((size_t)b * NCH + kg) * 64 + l] = 0x3F80; // bf16 1.0
      if (l == 0) sout[b * NCH + kg] = 0.f;
    }
    if (fstep[r] >= 0 && fstep[r] < CH - 1) { ps = fstep[r]; pr = r; }
  }

  const int byteA0 = (c * 128 + g * 16) ^ ((c & 7) << 4);
  const int byteA1 = (c * 128 + 64 + g * 16) ^ ((c & 7) << 4);
  int sigma = 0;

  auto renorm16 = [&](float* d) {
    float m = d[0];
#pragma unroll
    for (int i = 1; i < 16; ++i) m = fmaxf(m, d[i]);
    m = wave_fmax_all(m);
    int e = ((__float_as_int(m) >> 23) & 0xff) - 127;
    float s = __int_as_float((127 - e) << 23);
#pragma unroll
    for (int i = 0; i < 16; ++i) d[i] *= s;
    sigma += e;
  };
  auto save_row = [&](int r) {
    unsigned short v = smw[(r * 64 + l) ^ ((r & 7) << 3)];
    int kg = half * 16 + r;
    Vout[((size_t)b * NCH + kg) * 64 + l] = v;
    if (l == 0) sout[b * NCH + kg] = (float)sigma;
  };
  auto write_d = [&](const float* d) {
#pragma unroll
    for (int reg = 0; reg < 4; ++reg) {
      int row = g * 4 + reg;
      ushort4v wq;
#pragma unroll
      for (int n = 0; n < 4; ++n) wq[n] = f2bf(d[reg * 4 + n]);
      *reinterpret_cast<ushort4v*>(
          (char*)smw + ((row * 128 + c * 8) ^ ((row & 7) << 4))) = wq;
    }
  };

  if (dir == 0) {
    int tb0[4];
#pragma unroll
    for (int reg = 0; reg < 4; ++reg) tb0[reg] = (half * 16 + g * 4 + reg) * CH + 1;

    auto loadF = [&](unsigned* eu, int tl) {
#pragma unroll
      for (int reg = 0; reg < 4; ++reg) {
        int tr = min(tb0[reg] + tl, S_LEN - 1);
        float4 q = *reinterpret_cast<const float4*>(embase + (size_t)tr * 64 + 4 * c);
        eu[reg * 2 + 0] = (unsigned)f2bf(__expf(q.x)) | ((unsigned)f2bf(__expf(q.y)) << 16);
        eu[reg * 2 + 1] = (unsigned)f2bf(__expf(q.z)) | ((unsigned)f2bf(__expf(q.w)) << 16);
      }
    };
    auto bodyF = [&](const unsigned* eu, int tl) {
      short8 a0 = *reinterpret_cast<const short8*>((const char*)smw + byteA0);
      short8 a1 = *reinterpret_cast<const short8*>((const char*)smw + byteA1);
      f32x4 acc[4];
#pragma unroll
      for (int n = 0; n < 4; ++n) {
        f32x4 z = {0.f, 0.f, 0.f, 0.f};
        z = __builtin_amdgcn_mfma_f32_16x16x32_bf16(a0, Bf[0][n], z, 0, 0, 0);
        acc[n] = __builtin_amdgcn_mfma_f32_16x16x32_bf16(a1, Bf[1][n], z, 0, 0, 0);
      }
      float d[16];
#pragma unroll
      for (int reg = 0; reg < 4; ++reg) {
        d[reg * 4 + 0] = acc[0][reg] * bflo(eu[reg * 2 + 0]);
        d[reg * 4 + 1] = acc[1][reg] * bfhi(eu[reg * 2 + 0]);
        d[reg * 4 + 2] = acc[2][reg] * bflo(eu[reg * 2 + 1]);
        d[reg * 4 + 3] = acc[3][reg] * bfhi(eu[reg * 2 + 1]);
      }
      if ((tl & 3) == 3) renorm16(d);
      write_d(d);
      if (tl == ps) save_row(pr);
    };

    unsigned e0[8], e1[8], e2[8], e3[8];
    loadF(e0, 0); loadF(e1, 1); loadF(e2, 2); loadF(e3, 3);
#pragma unroll
    for (int tl = 0; tl < CH; tl += 4) {
      bodyF(e0, tl);     if (tl + 4 < CH) loadF(e0, tl + 4);
      bodyF(e1, tl + 1); if (tl + 5 < CH) loadF(e1, tl + 5);
      bodyF(e2, tl + 2); if (tl + 6 < CH) loadF(e2, tl + 6);
      bodyF(e3, tl + 3); if (tl + 7 < CH) loadF(e3, tl + 7);
    }
#pragma unroll
    for (int r = 0; r < 16; ++r)
      if (fstep[r] == CH - 1) save_row(r);
  } else {
    // ---- bwd: A rows are chains rc = c; E applied on A side ----
    const int tendl = min((half * 16 + c + 1) * CH, len - 1);

    auto loadB = [&](unsigned* eu, int tl) {
      int tr = max(tendl - tl, 0);
      const float* rowp = embase + (size_t)tr * 64;
      float4 q0 = *reinterpret_cast<const float4*>(rowp + 8 * g);
      float4 q1 = *reinterpret_cast<const float4*>(rowp + 8 * g + 4);
      float4 q2 = *reinterpret_cast<const float4*>(rowp + 32 + 8 * g);
      float4 q3 = *reinterpret_cast<const float4*>(rowp + 32 + 8 * g + 4);
      eu[0] = (unsigned)f2bf(__expf(q0.x)) | ((unsigned)f2bf(__expf(q0.y)) << 16);
      eu[1] = (unsigned)f2bf(__expf(q0.z)) | ((unsigned)f2bf(__expf(q0.w)) << 16);
      eu[2] = (unsigned)f2bf(__expf(q1.x)) | ((unsigned)f2bf(__expf(q1.y)) << 16);
      eu[3] = (unsigned)f2bf(__expf(q1.z)) | ((unsigned)f2bf(__expf(q1.w)) << 16);
      eu[4] = (unsigned)f2bf(__expf(q2.x)) | ((unsigned)f2bf(__expf(q2.y)) << 16);
      eu[5] = (unsigned)f2bf(__expf(q2.z)) | ((unsigned)f2bf(__expf(q2.w)) << 16);
      eu[6] = (unsigned)f2bf(__expf(q3.x)) | ((unsigned)f2bf(__expf(q3.y)) << 16);
      eu[7] = (unsigned)f2bf(__expf(q3.z)) | ((unsigned)f2bf(__expf(q3.w)) << 16);
    };
    auto bodyB = [&](const unsigned* eu, int tl) {
      short8 ar0 = *reinterpret_cast<const short8*>((const char*)smw + byteA0);
      short8 ar1 = *reinterpret_cast<const short8*>((const char*)smw + byteA1);
      short8 a0, a1;
#pragma unroll
      for (int j = 0; j < 8; ++j) {
        float E0 = (j & 1) ? bfhi(eu[j >> 1]) : bflo(eu[j >> 1]);
        float E1 = (j & 1) ? bfhi(eu[4 + (j >> 1)]) : bflo(eu[4 + (j >> 1)]);
        a0[j] = (short)f2bf(bf2f((unsigned short)ar0[j]) * E0);
        a1[j] = (short)f2bf(bf2f((unsigned short)ar1[j]) * E1);
      }
      f32x4 acc[4];
#pragma unroll
      for (int n = 0; n < 4; ++n) {
        f32x4 z = {0.f, 0.f, 0.f, 0.f};
        z = __builtin_amdgcn_mfma_f32_16x16x32_bf16(a0, Bf[0][n], z, 0, 0, 0);
        acc[n] = __builtin_amdgcn_mfma_f32_16x16x32_bf16(a1, Bf[1][n], z, 0, 0, 0);
      }
      float d[16];
#pragma unroll
      for (int reg = 0; reg < 4; ++reg)
#pragma unroll
        for (int n = 0; n < 4; ++n) d[reg * 4 + n] = acc[n][reg];
      if ((tl & 3) == 3) renorm16(d);
      write_d(d);
      if (tl == ps) save_row(pr);
    };

    unsigned e0[8], e1[8], e2[8], e3[8];
    loadB(e0, 0); loadB(e1, 1); loadB(e2, 2); loadB(e3, 3);
#pragma unroll
    for (int tl = 0; tl < CH; tl += 4) {
      bodyB(e0, tl);     if (tl + 4 < CH) loadB(e0, tl + 4);
      bodyB(e1, tl + 1); if (tl + 5 < CH) loadB(e1, tl + 5);
      bodyB(e2, tl + 2); if (tl + 6 < CH) loadB(e2, tl + 6);
      bodyB(e3, tl + 3); if (tl + 7 < CH) loadB(e3, tl + 7);
    }
#pragma unroll
    for (int r = 0; r < 16; ++r)
      if (fstep[r] == CH - 1) save_row(r);
  }
}

// ===== combine: rank-1 chunk stitching, one wave per batch =====
__global__ __launch_bounds__(256) void crf_combine(
    const float* __restrict__ trans, const int* __restrict__ lens,
    const unsigned short* __restrict__ Vf, const unsigned short* __restrict__ Vb,
    const float* __restrict__ sf, const float* __restrict__ sb,
    const float* __restrict__ score, const float* __restrict__ m0a,
    float* __restrict__ nll, int B)
{
  const int b = blockIdx.x * 4 + (threadIdx.x >> 6);
  if (b >= B) return;
  const int l = threadIdx.x & 63;
  const int len = lens[b];
  const int kb = (len >= 2) ? (len - 2) / CH : 0;

  const unsigned short* vf = Vf + (size_t)b * NCH * 64;
  const unsigned short* vb = Vb + (size_t)b * NCH * 64;
  const float tvec = __expf(trans[l * 64 + EOS_TAG]);

  float vf0 = bf2f(vf[l]);
  float lp;
  if (kb == 0) {
    lp = m0a[b] + LN2F * sf[b * NCH] + __logf(wave_sum_all(vf0 * tvec));
  } else {
    lp = m0a[b] + LN2F * (sf[b * NCH] + sb[b * NCH + 1])
       + __logf(wave_sum_all(vf0 * bf2f(vb[1 * 64 + l])));
    for (int k = 1; k < kb; ++k) {
      float vfk = bf2f(vf[(size_t)k * 64 + l]);
      lp += LN2F * sb[b * NCH + k + 1]
          + __logf(wave_sum_all(vfk * bf2f(vb[(size_t)(k + 1) * 64 + l])))
          - __logf(wave_sum_all(vfk));
    }
    float vfb = bf2f(vf[(size_t)kb * 64 + l]);
    lp += __logf(wave_sum_all(vfb * tvec)) - __logf(wave_sum_all(vfb));
  }

  if (l == 0) nll[b] = lp - score[b];
}

__global__ __launch_bounds__(64) void crf_reduce(
    const float* __restrict__ nll, float* __restrict__ out, int B) {
  float s = 0.f;
  for (int i = threadIdx.x; i < B; i += 64) s += nll[i];
  s = wave_sum_all(s);
  if (threadIdx.x == 0) out[0] = s;
}

// ===== fallback: monolithic per-batch forward (VALU, linear space) =====
__global__ __launch_bounds__(64) void crf_mono(
    const float* __restrict__ em, const int* __restrict__ tags,
    const float* __restrict__ mask, const float* __restrict__ trans,
    float* __restrict__ partial)
{
  const int b = blockIdx.x;
  const int l = threadIdx.x;
  const float* emb = em + (size_t)b * S_LEN * 64;
  const float* mb = mask + (size_t)b * S_LEN;
  float lenf = 0.f;
  for (int t = l; t < S_LEN; t += 64) lenf += mb[t];
  lenf = wave_sum_all(lenf);
  const int len = max(1, min(S_LEN, (int)(lenf + 0.5f)));

  float p[64];
#pragma unroll
  for (int i = 0; i < 64; ++i) p[i] = __expf(trans[i * 64 + l]) * 0.015625f;

  const int* tb = tags + (size_t)b * S_LEN;
  float sc = 0.f;
  for (int tt = 1 + l; tt <= len - 1; tt += 64)
    sc += emb[(size_t)tt * 64 + tb[tt]] + trans[tb[tt - 1] * 64 + tb[tt]];
  sc = wave_sum_all(sc);
  sc += trans[BOS_TAG * 64 + tb[0]] + emb[tb[0]] + trans[tb[len - 1] * 64 + EOS_TAG];

  float a0 = trans[BOS_TAG * 64 + l] + emb[l];
  float m0 = wave_fmax_all(a0);
  float v = __expf(a0 - m0);
  int sigma = 0;
  for (int t = 1; t <= len - 1; ++t) {
    float E = __expf(emb[(size_t)t * 64 + l]);
    int xi = __float_as_int(v);
    float s0 = 0.f, s1 = 0.f, s2 = 0.f, s3 = 0.f;
#pragma unroll
    for (int i = 0; i < 64; i += 4) {
      s0 = fmaf(__int_as_float(__builtin_amdgcn_readlane(xi, i + 0)), p[i + 0], s0);
      s1 = fmaf(__int_as_float(__builtin_amdgcn_readlane(xi, i + 1)), p[i + 1], s1);
      s2 = fmaf(__int_as_float(__builtin_amdgcn_readlane(xi, i + 2)), p[i + 2], s2);
      s3 = fmaf(__int_as_float(__builtin_amdgcn_readlane(xi, i + 3)), p[i + 3], s3);
    }
    v = ((s0 + s1) + (s2 + s3)) * E;
    float m = wave_fmax_all(v);
    int e = ((__float_as_int(m) >> 23) & 0xff) - 127;
    sigma += e + 6;
    v *= __int_as_float((127 - e) << 23);
  }
  float tvec = __expf(trans[l * 64 + EOS_TAG]);
  float lp = m0 + LN2F * (float)sigma + __logf(wave_sum_all(v * tvec));
  if (l == 0) partial[b] = lp - sc;
}

extern "C" void kernel_launch(void* const* d_in, const int* in_sizes, int n_in,
                              void* d_out, int out_size, void* d_ws, size_t ws_size,
                              hipStream_t stream) {
  const float* em = (const float*)d_in[0];
  const int* tags = (const int*)d_in[1];
  const float* mask = (const float*)d_in[2];
  const float* trans = (const float*)d_in[3];
  float* out = (float*)d_out;

  const int B = in_sizes[1] / S_LEN;

  // layout: floats [sf | sb | score | m0a | nll], int [lens], ushort [Vf | Vb]
  const size_t nSig = (size_t)B * NCH;
  const size_t nV   = (size_t)B * NCH * 64;
  const size_t need = (2 * nSig + 3 * (size_t)B) * sizeof(float)
                    + (size_t)B * sizeof(int)
                    + 2 * nV * sizeof(unsigned short);

  if (ws_size >= need) {
    float* sf    = (float*)d_ws;
    float* sb    = sf + nSig;
    float* score = sb + nSig;
    float* m0a   = score + B;
    float* nll   = m0a + B;
    int*   lens  = (int*)(nll + B);
    unsigned short* Vf = (unsigned short*)(lens + B);
    unsigned short* Vb = Vf + nV;

    crf_prep<<<B, 256, 0, stream>>>(em, tags, mask, trans, lens, score, m0a);
    const int nwaves = 2 * B * WPB;
    crf_chunk_mfma<<<(nwaves + 3) / 4, 256, 0, stream>>>(
        em, trans, lens, Vf, Vb, sf, sb, m0a, B);
    crf_combine<<<(B + 3) / 4, 256, 0, stream>>>(
        trans, lens, Vf, Vb, sf, sb, score, m0a, nll, B);
    crf_reduce<<<1, 64, 0, stream>>>(nll, out, B);
  } else {
    float* partial = (float*)d_ws;
    crf_mono<<<B, 64, 0, stream>>>(em, tags, mask, trans, partial);
    crf_reduce<<<1, 64, 0, stream>>>(partial, out, B);
  }
}